// Round 6
// baseline (250.314 us; speedup 1.0000x reference)
//
#include <hip/hip_runtime.h>
#include <cstdint>

#define PERB 262144   // C*H*H = N*D elements per batch

typedef __attribute__((ext_vector_type(8))) short bf16x8;
typedef __attribute__((ext_vector_type(4))) float f32x4;
typedef unsigned short ushort_t;

__device__ __forceinline__ uint16_t f2bf(float f) {
    uint32_t u = __float_as_uint(f);
    u += 0x7fff + ((u >> 16) & 1);   // RNE
    return (uint16_t)(u >> 16);
}

// ---------------------------------------------------------------------------
// Kernel 0: convert the 4 weight matrices (256x256 fp32) to bf16.
// ---------------------------------------------------------------------------
__global__ __launch_bounds__(256) void wcvt_kernel(
    const float* __restrict__ wq, const float* __restrict__ wk,
    const float* __restrict__ wv, const float* __restrict__ wo,
    ushort_t* __restrict__ oq, ushort_t* __restrict__ ok,
    ushort_t* __restrict__ ov, ushort_t* __restrict__ oo)
{
    const int which = blockIdx.x >> 6;
    const int idx = ((blockIdx.x & 63) * 256 + threadIdx.x) * 4;
    const float* src = which == 0 ? wq : which == 1 ? wk : which == 2 ? wv : wo;
    ushort_t* dst    = which == 0 ? oq : which == 1 ? ok : which == 2 ? ov : oo;
    const float4 v = *(const float4*)&src[idx];
    uint2 p;
    p.x = (uint32_t)f2bf(v.x) | ((uint32_t)f2bf(v.y) << 16);
    p.y = (uint32_t)f2bf(v.z) | ((uint32_t)f2bf(v.w) << 16);
    *(uint2*)&dst[idx] = p;
}

// ---------------------------------------------------------------------------
// Kernel 1: LayerNorm over channel axis; output bf16 (same flat layout).
// ---------------------------------------------------------------------------
__global__ __launch_bounds__(256) void ln_kernel(
    const float* __restrict__ x, const float* __restrict__ gam,
    const float* __restrict__ bet, ushort_t* __restrict__ X)
{
    const int blk = blockIdx.x;
    const int b   = blk >> 4;
    const int sp0 = (blk & 15) << 6;
    const int tid = threadIdx.x;
    const int spl = tid & 63;
    const int cg  = tid >> 6;
    const int c0  = cg << 6;
    const int sp  = sp0 + spl;
    const float* xb = x + (size_t)b * PERB + sp;

    float vals[64];
    float s = 0.f, sq = 0.f;
#pragma unroll
    for (int i = 0; i < 64; ++i) {
        float v = xb[(size_t)(c0 + i) * 1024];
        vals[i] = v; s += v; sq += v * v;
    }
    __shared__ float rs[4][64];
    __shared__ float rq[4][64];
    rs[cg][spl] = s; rq[cg][spl] = sq;
    __syncthreads();
    const float ts = rs[0][spl] + rs[1][spl] + rs[2][spl] + rs[3][spl];
    const float tq = rq[0][spl] + rq[1][spl] + rq[2][spl] + rq[3][spl];
    const float mean = ts * (1.f / 256.f);
    const float var  = tq * (1.f / 256.f) - mean * mean;
    const float rstd = rsqrtf(var + 1e-5f);

    ushort_t* Xb = X + (size_t)b * PERB + sp;
#pragma unroll
    for (int i = 0; i < 64; ++i) {
        const int c = c0 + i;
        Xb[(size_t)c * 1024] = f2bf((vals[i] - mean) * rstd * gam[c] + bet[c]);
    }
}

// ---------------------------------------------------------------------------
// Kernel 2: MFMA fused Q/K/V projection (bf16 in, bf16 out). Unchanged.
// ---------------------------------------------------------------------------
__global__ __launch_bounds__(256, 3) void qkv_kernel(
    const ushort_t* __restrict__ X,
    const ushort_t* __restrict__ wq, const float* __restrict__ bq,
    const ushort_t* __restrict__ wk, const float* __restrict__ bk,
    const ushort_t* __restrict__ wv, const float* __restrict__ bv,
    ushort_t* __restrict__ Q, ushort_t* __restrict__ K, ushort_t* __restrict__ V)
{
    __shared__ __align__(16) ushort_t Xl[512 * 8];
    __shared__ __align__(16) ushort_t Wl[3][512 * 8];

    const int blk = blockIdx.x;
    const int m0  = (blk >> 2) << 6;
    const int n0  = (blk & 3) << 6;
    const int tid = threadIdx.x;
    const int w    = tid >> 6;
    const int lane = tid & 63;
    const int quad = lane >> 4;
    const int c    = lane & 15;

    f32x4 acc[3][4];
#pragma unroll
    for (int o3 = 0; o3 < 3; ++o3)
#pragma unroll
        for (int i = 0; i < 4; ++i) acc[o3][i] = (f32x4){0.f, 0.f, 0.f, 0.f};

    for (int kc = 0; kc < 4; ++kc) {
        const int k0 = kc << 6;
        __syncthreads();
#pragma unroll
        for (int i = 0; i < 2; ++i) {
            const int id = tid + i * 256;
            const int kq = id >> 6, m = id & 63;
            *(bf16x8*)&Xl[id * 8] = *(const bf16x8*)&X[(size_t)(m0 + m) * 256 + k0 + kq * 8];
        }
#pragma unroll
        for (int i = 0; i < 2; ++i) {
            const int id = tid + i * 256;
            const int kq = id >> 6, n = id & 63;
            const size_t g = (size_t)(n0 + n) * 256 + k0 + kq * 8;
            *(bf16x8*)&Wl[0][id * 8] = *(const bf16x8*)&wq[g];
            *(bf16x8*)&Wl[1][id * 8] = *(const bf16x8*)&wk[g];
            *(bf16x8*)&Wl[2][id * 8] = *(const bf16x8*)&wv[g];
        }
        __syncthreads();
#pragma unroll
        for (int ks = 0; ks < 2; ++ks) {
            const int kq = ks * 4 + quad;
            bf16x8 af[4];
#pragma unroll
            for (int msub = 0; msub < 4; ++msub)
                af[msub] = *(const bf16x8*)&Xl[(kq * 64 + msub * 16 + c) * 8];
            bf16x8 bw[3];
#pragma unroll
            for (int o3 = 0; o3 < 3; ++o3)
                bw[o3] = *(const bf16x8*)&Wl[o3][(kq * 64 + w * 16 + c) * 8];
#pragma unroll
            for (int o3 = 0; o3 < 3; ++o3)
#pragma unroll
                for (int msub = 0; msub < 4; ++msub)
                    acc[o3][msub] = __builtin_amdgcn_mfma_f32_16x16x32_bf16(
                        bw[o3], af[msub], acc[o3][msub], 0, 0, 0);
        }
    }

    const int n = n0 + w * 16 + quad * 4;
    const float4 bq4 = *(const float4*)&bq[n];
    const float4 bk4 = *(const float4*)&bk[n];
    const float4 bv4 = *(const float4*)&bv[n];
    ushort_t* outs[3] = {Q, K, V};
    const float4 bias[3] = {bq4, bk4, bv4};
#pragma unroll
    for (int msub = 0; msub < 4; ++msub) {
        const size_t m = (size_t)(m0 + msub * 16 + c);
#pragma unroll
        for (int o3 = 0; o3 < 3; ++o3) {
            const f32x4 a = acc[o3][msub];
            uint2 p;
            p.x = (uint32_t)f2bf(a[0] + bias[o3].x) | ((uint32_t)f2bf(a[1] + bias[o3].y) << 16);
            p.y = (uint32_t)f2bf(a[2] + bias[o3].z) | ((uint32_t)f2bf(a[3] + bias[o3].w) << 16);
            *(uint2*)&outs[o3][m * 256 + n] = p;
        }
    }
}

// ---------------------------------------------------------------------------
// Kernel 3: MFMA flash attention, round-6.
//  Changes vs round 5: bias table no longer staged in LDS -- read from global
//  (L1/L2-resident, coalesced consecutive dwords). LDS = 28KB -> 5 blocks/CU,
//  all 1024 blocks co-resident. launch_bounds(256,5).
// ---------------------------------------------------------------------------
#define C1F 0.09016844005556022f   // 0.0625 * log2(e)
#define LOG2EF 1.4426950408889634f

__global__ __launch_bounds__(256, 5) void attn_kernel(
    const ushort_t* __restrict__ Q, const ushort_t* __restrict__ K,
    const ushort_t* __restrict__ V, const float* __restrict__ relb,
    ushort_t* __restrict__ O)
{
    // LDS map (bytes):
    //   [0, 16384)       P: 128 rows x 128B, 16B-unit swizzle; Q staging at start
    //   [16384, 20480)   K: granule (q=s>>3)*1024 + nn*16
    //   [20480, 28672)   V dbuf: buf*4096 + s*128, 16B-unit swizzle ^(s&7)
    __shared__ __align__(16) unsigned char smem[28672];
    char* Pb = (char*)smem;
    char* Kl = (char*)(smem + 16384);
    char* Vl = (char*)(smem + 20480);

    const int blk = blockIdx.x;
    const int bh  = blk & 127;
    const int mt  = blk >> 7;
    const int b   = bh >> 3;
    const int h   = bh & 7;
    const int m0  = mt << 7;
    const int tid = threadIdx.x;
    const int w    = tid >> 6;
    const int lane = tid & 63;
    const int quad = lane >> 4;
    const int c    = lane & 15;

    const size_t base = (size_t)b * PERB + (size_t)h * 32768;
    const ushort_t* Qg = Q + base;
    const ushort_t* Kg = K + base;
    const ushort_t* Vg = V + base;
    const float* rbh = relb + h * 3969;

    // ---- stage Q [32s x 128m] into Pb (granule layout), then read frags ----
    {
        const int mm = tid & 127;
        const int sg = tid >> 7;
        union { bf16x8 v; uint16_t u[8]; } g0, g1;
#pragma unroll
        for (int j = 0; j < 8; ++j)
            g0.u[j] = Qg[(size_t)(sg * 16 + j) * 1024 + m0 + mm];
#pragma unroll
        for (int j = 0; j < 8; ++j)
            g1.u[j] = Qg[(size_t)(sg * 16 + 8 + j) * 1024 + m0 + mm];
        *(bf16x8*)(Pb + (sg * 2 + 0) * 2048 + mm * 16) = g0.v;
        *(bf16x8*)(Pb + (sg * 2 + 1) * 2048 + mm * 16) = g1.v;
    }
    __syncthreads();
    bf16x8 qfrag[8];
#pragma unroll
    for (int msub = 0; msub < 8; ++msub)
        qfrag[msub] = *(const bf16x8*)(Pb + quad * 2048 + (msub * 16 + c) * 16);

    // per-msub bias m-offset: idx = noff(n) + moff(m)
    int moff[8];
#pragma unroll
    for (int msub = 0; msub < 8; ++msub) {
        const int m = m0 + msub * 16 + c;
        moff[msub] = 1984 - (m >> 5) * 63 - (m & 31);
    }

    // accumulators
    f32x4 oacc[2][2], dacc[2];
#pragma unroll
    for (int i = 0; i < 2; ++i) {
        dacc[i] = (f32x4){0.f, 0.f, 0.f, 0.f};
#pragma unroll
        for (int j = 0; j < 2; ++j) oacc[i][j] = (f32x4){0.f, 0.f, 0.f, 0.f};
    }
    bf16x8 onesf;
#pragma unroll
    for (int j = 0; j < 8; ++j) onesf[j] = (short)0x3F80;

    // staging thread coords + hoisted LDS addresses
    const int knn = tid & 63, ksg = tid >> 6;   // K: 8 s-values for column knn
    const int vs  = tid >> 3, vng = tid & 7;    // V: unit16 vng of row vs
    const int kWr = ksg * 1024 + knn * 16;
    const int vWr = vs * 128 + ((vng ^ (vs & 7)) << 4);
    const int kRd = quad * 1024 + (w * 16 + c) * 16;
    const int pWr = c * 128 + (((2 * w + (quad >> 1)) ^ (c & 7)) << 4) + ((quad & 1) << 3);
    const int c7  = c & 7;

    // prologue: prefetch chunk 0
    uint32_t kpre[8]; bf16x8 vpre;
#pragma unroll
    for (int j = 0; j < 8; ++j) kpre[j] = Kg[(size_t)(ksg * 8 + j) * 1024 + knn];
    vpre = *(const bf16x8*)&Vg[(size_t)vs * 1024 + vng * 8];

    for (int ch = 0; ch < 16; ++ch) {
        const int n0c = ch << 6;
        const int cb  = ch & 1;

        // ---- write prefetched K/V to LDS ----
        {
            uint4 kp;
            kp.x = kpre[0] | (kpre[1] << 16);
            kp.y = kpre[2] | (kpre[3] << 16);
            kp.z = kpre[4] | (kpre[5] << 16);
            kp.w = kpre[6] | (kpre[7] << 16);
            *(uint4*)(Kl + kWr) = kp;
            *(bf16x8*)(Vl + cb * 4096 + vWr) = vpre;
        }
        __syncthreads();   // staging visible; prev PV done for all waves

        // ---- prefetch next chunk into regs (overlaps S phase) ----
        {
            const int n0n = ((ch + 1) & 15) << 6;
#pragma unroll
            for (int j = 0; j < 8; ++j)
                kpre[j] = Kg[(size_t)(ksg * 8 + j) * 1024 + n0n + knn];
            vpre = *(const bf16x8*)&Vg[(size_t)vs * 1024 + n0n + vng * 8];
        }

        // ---- S phase ----
        const bf16x8 kf = *(const bf16x8*)(Kl + kRd);
        f32x4 sacc[8];
#pragma unroll
        for (int msub = 0; msub < 8; ++msub) {
            const f32x4 z = {0.f, 0.f, 0.f, 0.f};
            sacc[msub] = __builtin_amdgcn_mfma_f32_16x16x32_bf16(kf, qfrag[msub], z, 0, 0, 0);
        }

        // ---- bias (global, L1/L2-hit) + exp2 + trunc-pack + P write ----
        const int nbase = n0c + w * 16 + quad * 4;
        const int nidx0 = (nbase >> 5) * 63 + (nbase & 31);  // 4 consecutive ints follow
#pragma unroll
        for (int msub = 0; msub < 8; ++msub) {
            const float* bp = rbh + nidx0 + moff[msub];
            float p[4];
#pragma unroll
            for (int r = 0; r < 4; ++r)
                p[r] = __builtin_amdgcn_exp2f(fmaf(bp[r], LOG2EF, sacc[msub][r] * C1F));
            uint2 pk;
            pk.x = __builtin_amdgcn_perm(__float_as_uint(p[1]), __float_as_uint(p[0]), 0x07060302u);
            pk.y = __builtin_amdgcn_perm(__float_as_uint(p[3]), __float_as_uint(p[2]), 0x07060302u);
            *(uint2*)(Pb + msub * 2048 + pWr) = pk;
        }
        __syncthreads();   // P (and V) ready for PV

        // ---- PV phase: wave w owns msub {2w, 2w+1} ----
#pragma unroll
        for (int kstep = 0; kstep < 2; ++kstep) {
            const int u = ((kstep * 4 + quad) ^ c7) << 4;
            const bf16x8 vf0 = *(const bf16x8*)(Vl + cb * 4096 + c * 128 + u);
            const bf16x8 vf1 = *(const bf16x8*)(Vl + cb * 4096 + (16 + c) * 128 + u);
#pragma unroll
            for (int mi = 0; mi < 2; ++mi) {
                const bf16x8 pf = *(const bf16x8*)(Pb + ((w * 2 + mi) * 16 + c) * 128 + u);
                oacc[0][mi] = __builtin_amdgcn_mfma_f32_16x16x32_bf16(vf0, pf, oacc[0][mi], 0, 0, 0);
                oacc[1][mi] = __builtin_amdgcn_mfma_f32_16x16x32_bf16(vf1, pf, oacc[1][mi], 0, 0, 0);
                dacc[mi]    = __builtin_amdgcn_mfma_f32_16x16x32_bf16(onesf, pf, dacc[mi], 0, 0, 0);
            }
        }
    }

    // ---- epilogue: scale by 1/denominator, write O ----
    ushort_t* Ob = O + base;
#pragma unroll
    for (int mi = 0; mi < 2; ++mi) {
        const float inv = 1.0f / dacc[mi][0];
        const int m = m0 + (w * 2 + mi) * 16 + c;
#pragma unroll
        for (int ssub = 0; ssub < 2; ++ssub)
#pragma unroll
            for (int r = 0; r < 4; ++r)
                Ob[(size_t)(ssub * 16 + quad * 4 + r) * 1024 + m] = f2bf(oacc[ssub][mi][r] * inv);
    }
}

// ---------------------------------------------------------------------------
// Kernel 4: MFMA output projection + bias + residual. Unchanged.
// ---------------------------------------------------------------------------
__global__ __launch_bounds__(256, 4) void oproj_kernel(
    const ushort_t* __restrict__ A, const ushort_t* __restrict__ wo,
    const float* __restrict__ bo, const float* __restrict__ x,
    float* __restrict__ out)
{
    __shared__ __align__(16) ushort_t Al[512 * 8];
    __shared__ __align__(16) ushort_t Wl[512 * 8];

    const int blk = blockIdx.x;
    const int m0  = (blk >> 2) << 6;
    const int n0  = (blk & 3) << 6;
    const int tid = threadIdx.x;
    const int w    = tid >> 6;
    const int lane = tid & 63;
    const int quad = lane >> 4;
    const int c    = lane & 15;

    f32x4 acc[4];
#pragma unroll
    for (int i = 0; i < 4; ++i) acc[i] = (f32x4){0.f, 0.f, 0.f, 0.f};

    for (int kc = 0; kc < 4; ++kc) {
        const int k0 = kc << 6;
        __syncthreads();
#pragma unroll
        for (int i = 0; i < 2; ++i) {
            const int id = tid + i * 256;
            const int kq = id >> 6, mn = id & 63;
            *(bf16x8*)&Al[id * 8] = *(const bf16x8*)&A [(size_t)(m0 + mn) * 256 + k0 + kq * 8];
            *(bf16x8*)&Wl[id * 8] = *(const bf16x8*)&wo[(size_t)(n0 + mn) * 256 + k0 + kq * 8];
        }
        __syncthreads();
#pragma unroll
        for (int ks = 0; ks < 2; ++ks) {
            const int kq = ks * 4 + quad;
            const bf16x8 bw = *(const bf16x8*)&Wl[(kq * 64 + w * 16 + c) * 8];
#pragma unroll
            for (int msub = 0; msub < 4; ++msub) {
                const bf16x8 af = *(const bf16x8*)&Al[(kq * 64 + msub * 16 + c) * 8];
                acc[msub] = __builtin_amdgcn_mfma_f32_16x16x32_bf16(bw, af, acc[msub], 0, 0, 0);
            }
        }
    }

    const int n = n0 + w * 16 + quad * 4;
    const float4 bo4 = *(const float4*)&bo[n];
#pragma unroll
    for (int msub = 0; msub < 4; ++msub) {
        const size_t g = (size_t)(m0 + msub * 16 + c) * 256 + n;
        const float4 r = *(const float4*)&x[g];
        float4 t;
        t.x = acc[msub][0] + bo4.x + r.x;
        t.y = acc[msub][1] + bo4.y + r.y;
        t.z = acc[msub][2] + bo4.z + r.z;
        t.w = acc[msub][3] + bo4.w + r.w;
        *(float4*)&out[g] = t;
    }
}

// ---------------------------------------------------------------------------
extern "C" void kernel_launch(void* const* d_in, const int* in_sizes, int n_in,
                              void* d_out, int out_size, void* d_ws, size_t ws_size,
                              hipStream_t stream)
{
    (void)in_sizes; (void)n_in; (void)out_size; (void)ws_size;
    const float* x   = (const float*)d_in[0];
    const float* lng = (const float*)d_in[1];
    const float* lnb = (const float*)d_in[2];
    const float* wq  = (const float*)d_in[3];
    const float* bq  = (const float*)d_in[4];
    const float* wk  = (const float*)d_in[5];
    const float* bk  = (const float*)d_in[6];
    const float* wv  = (const float*)d_in[7];
    const float* bv  = (const float*)d_in[8];
    const float* wo  = (const float*)d_in[9];
    const float* bo  = (const float*)d_in[10];
    const float* rb  = (const float*)d_in[11];
    // d_in[12] (rel_idx) unused: index recomputed analytically in-kernel.

    ushort_t* ws = (ushort_t*)d_ws;
    ushort_t* Xbf = ws;                       // 4194304 elems each
    ushort_t* Qbf = ws + 1 * 4194304;
    ushort_t* Kbf = ws + 2 * 4194304;
    ushort_t* Vbf = ws + 3 * 4194304;
    ushort_t* Obf = ws + 4 * 4194304;
    ushort_t* Wqb = ws + 5 * 4194304;
    ushort_t* Wkb = Wqb + 65536;
    ushort_t* Wvb = Wkb + 65536;
    ushort_t* Wob = Wvb + 65536;
    float* out = (float*)d_out;

    hipLaunchKernelGGL(wcvt_kernel,  dim3(256),  dim3(256), 0, stream,
                       wq, wk, wv, wo, Wqb, Wkb, Wvb, Wob);
    hipLaunchKernelGGL(ln_kernel,    dim3(256),  dim3(256), 0, stream, x, lng, lnb, Xbf);
    hipLaunchKernelGGL(qkv_kernel,   dim3(1024), dim3(256), 0, stream,
                       Xbf, Wqb, bq, Wkb, bk, Wvb, bv, Qbf, Kbf, Vbf);
    hipLaunchKernelGGL(attn_kernel,  dim3(1024), dim3(256), 0, stream, Qbf, Kbf, Vbf, rb, Obf);
    hipLaunchKernelGGL(oproj_kernel, dim3(1024), dim3(256), 0, stream, Obf, Wob, bo, x, out);
}

// Round 7
// 175.666 us; speedup vs baseline: 1.4249x; 1.4249x over previous
//
#include <hip/hip_runtime.h>
#include <cstdint>

#define PERB 262144   // C*H*H = N*D elements per batch

typedef __attribute__((ext_vector_type(8))) short bf16x8;
typedef __attribute__((ext_vector_type(4))) float f32x4;
typedef unsigned short ushort_t;

__device__ __forceinline__ uint16_t f2bf(float f) {
    uint32_t u = __float_as_uint(f);
    u += 0x7fff + ((u >> 16) & 1);   // RNE
    return (uint16_t)(u >> 16);
}

// ---------------------------------------------------------------------------
// Kernel 0: convert the 4 weight matrices (256x256 fp32) to bf16.
// ---------------------------------------------------------------------------
__global__ __launch_bounds__(256) void wcvt_kernel(
    const float* __restrict__ wq, const float* __restrict__ wk,
    const float* __restrict__ wv, const float* __restrict__ wo,
    ushort_t* __restrict__ oq, ushort_t* __restrict__ ok,
    ushort_t* __restrict__ ov, ushort_t* __restrict__ oo)
{
    const int which = blockIdx.x >> 6;
    const int idx = ((blockIdx.x & 63) * 256 + threadIdx.x) * 4;
    const float* src = which == 0 ? wq : which == 1 ? wk : which == 2 ? wv : wo;
    ushort_t* dst    = which == 0 ? oq : which == 1 ? ok : which == 2 ? ov : oo;
    const float4 v = *(const float4*)&src[idx];
    uint2 p;
    p.x = (uint32_t)f2bf(v.x) | ((uint32_t)f2bf(v.y) << 16);
    p.y = (uint32_t)f2bf(v.z) | ((uint32_t)f2bf(v.w) << 16);
    *(uint2*)&dst[idx] = p;
}

// ---------------------------------------------------------------------------
// Kernel 1: LayerNorm over channel axis; output bf16 (same flat layout).
// ---------------------------------------------------------------------------
__global__ __launch_bounds__(256) void ln_kernel(
    const float* __restrict__ x, const float* __restrict__ gam,
    const float* __restrict__ bet, ushort_t* __restrict__ X)
{
    const int blk = blockIdx.x;
    const int b   = blk >> 4;
    const int sp0 = (blk & 15) << 6;
    const int tid = threadIdx.x;
    const int spl = tid & 63;
    const int cg  = tid >> 6;
    const int c0  = cg << 6;
    const int sp  = sp0 + spl;
    const float* xb = x + (size_t)b * PERB + sp;

    float vals[64];
    float s = 0.f, sq = 0.f;
#pragma unroll
    for (int i = 0; i < 64; ++i) {
        float v = xb[(size_t)(c0 + i) * 1024];
        vals[i] = v; s += v; sq += v * v;
    }
    __shared__ float rs[4][64];
    __shared__ float rq[4][64];
    rs[cg][spl] = s; rq[cg][spl] = sq;
    __syncthreads();
    const float ts = rs[0][spl] + rs[1][spl] + rs[2][spl] + rs[3][spl];
    const float tq = rq[0][spl] + rq[1][spl] + rq[2][spl] + rq[3][spl];
    const float mean = ts * (1.f / 256.f);
    const float var  = tq * (1.f / 256.f) - mean * mean;
    const float rstd = rsqrtf(var + 1e-5f);

    ushort_t* Xb = X + (size_t)b * PERB + sp;
#pragma unroll
    for (int i = 0; i < 64; ++i) {
        const int c = c0 + i;
        Xb[(size_t)c * 1024] = f2bf((vals[i] - mean) * rstd * gam[c] + bet[c]);
    }
}

// ---------------------------------------------------------------------------
// Kernel 2: MFMA fused Q/K/V projection (bf16 in, bf16 out). Unchanged.
// ---------------------------------------------------------------------------
__global__ __launch_bounds__(256, 3) void qkv_kernel(
    const ushort_t* __restrict__ X,
    const ushort_t* __restrict__ wq, const float* __restrict__ bq,
    const ushort_t* __restrict__ wk, const float* __restrict__ bk,
    const ushort_t* __restrict__ wv, const float* __restrict__ bv,
    ushort_t* __restrict__ Q, ushort_t* __restrict__ K, ushort_t* __restrict__ V)
{
    __shared__ __align__(16) ushort_t Xl[512 * 8];
    __shared__ __align__(16) ushort_t Wl[3][512 * 8];

    const int blk = blockIdx.x;
    const int m0  = (blk >> 2) << 6;
    const int n0  = (blk & 3) << 6;
    const int tid = threadIdx.x;
    const int w    = tid >> 6;
    const int lane = tid & 63;
    const int quad = lane >> 4;
    const int c    = lane & 15;

    f32x4 acc[3][4];
#pragma unroll
    for (int o3 = 0; o3 < 3; ++o3)
#pragma unroll
        for (int i = 0; i < 4; ++i) acc[o3][i] = (f32x4){0.f, 0.f, 0.f, 0.f};

    for (int kc = 0; kc < 4; ++kc) {
        const int k0 = kc << 6;
        __syncthreads();
#pragma unroll
        for (int i = 0; i < 2; ++i) {
            const int id = tid + i * 256;
            const int kq = id >> 6, m = id & 63;
            *(bf16x8*)&Xl[id * 8] = *(const bf16x8*)&X[(size_t)(m0 + m) * 256 + k0 + kq * 8];
        }
#pragma unroll
        for (int i = 0; i < 2; ++i) {
            const int id = tid + i * 256;
            const int kq = id >> 6, n = id & 63;
            const size_t g = (size_t)(n0 + n) * 256 + k0 + kq * 8;
            *(bf16x8*)&Wl[0][id * 8] = *(const bf16x8*)&wq[g];
            *(bf16x8*)&Wl[1][id * 8] = *(const bf16x8*)&wk[g];
            *(bf16x8*)&Wl[2][id * 8] = *(const bf16x8*)&wv[g];
        }
        __syncthreads();
#pragma unroll
        for (int ks = 0; ks < 2; ++ks) {
            const int kq = ks * 4 + quad;
            bf16x8 af[4];
#pragma unroll
            for (int msub = 0; msub < 4; ++msub)
                af[msub] = *(const bf16x8*)&Xl[(kq * 64 + msub * 16 + c) * 8];
            bf16x8 bw[3];
#pragma unroll
            for (int o3 = 0; o3 < 3; ++o3)
                bw[o3] = *(const bf16x8*)&Wl[o3][(kq * 64 + w * 16 + c) * 8];
#pragma unroll
            for (int o3 = 0; o3 < 3; ++o3)
#pragma unroll
                for (int msub = 0; msub < 4; ++msub)
                    acc[o3][msub] = __builtin_amdgcn_mfma_f32_16x16x32_bf16(
                        bw[o3], af[msub], acc[o3][msub], 0, 0, 0);
        }
    }

    const int n = n0 + w * 16 + quad * 4;
    const float4 bq4 = *(const float4*)&bq[n];
    const float4 bk4 = *(const float4*)&bk[n];
    const float4 bv4 = *(const float4*)&bv[n];
    ushort_t* outs[3] = {Q, K, V};
    const float4 bias[3] = {bq4, bk4, bv4};
#pragma unroll
    for (int msub = 0; msub < 4; ++msub) {
        const size_t m = (size_t)(m0 + msub * 16 + c);
#pragma unroll
        for (int o3 = 0; o3 < 3; ++o3) {
            const f32x4 a = acc[o3][msub];
            uint2 p;
            p.x = (uint32_t)f2bf(a[0] + bias[o3].x) | ((uint32_t)f2bf(a[1] + bias[o3].y) << 16);
            p.y = (uint32_t)f2bf(a[2] + bias[o3].z) | ((uint32_t)f2bf(a[3] + bias[o3].w) << 16);
            *(uint2*)&outs[o3][m * 256 + n] = p;
        }
    }
}

// ---------------------------------------------------------------------------
// Kernel 3: MFMA flash attention, round-7.
//  Round 6's bias-from-global kept; launch_bounds relaxed 5 -> 4 waves/EU
//  (round 6's (256,5) forced VGPR 48 -> massive scratch spills: FETCH 165MB).
//  4 blocks/CU x 256 CU = exactly 1024 blocks co-resident, no spill.
// ---------------------------------------------------------------------------
#define C1F 0.09016844005556022f   // 0.0625 * log2(e)
#define LOG2EF 1.4426950408889634f

__global__ __launch_bounds__(256, 4) void attn_kernel(
    const ushort_t* __restrict__ Q, const ushort_t* __restrict__ K,
    const ushort_t* __restrict__ V, const float* __restrict__ relb,
    ushort_t* __restrict__ O)
{
    // LDS map (bytes):
    //   [0, 16384)       P: 128 rows x 128B, 16B-unit swizzle; Q staging at start
    //   [16384, 20480)   K: granule (q=s>>3)*1024 + nn*16
    //   [20480, 28672)   V dbuf: buf*4096 + s*128, 16B-unit swizzle ^(s&7)
    __shared__ __align__(16) unsigned char smem[28672];
    char* Pb = (char*)smem;
    char* Kl = (char*)(smem + 16384);
    char* Vl = (char*)(smem + 20480);

    const int blk = blockIdx.x;
    const int bh  = blk & 127;
    const int mt  = blk >> 7;
    const int b   = bh >> 3;
    const int h   = bh & 7;
    const int m0  = mt << 7;
    const int tid = threadIdx.x;
    const int w    = tid >> 6;
    const int lane = tid & 63;
    const int quad = lane >> 4;
    const int c    = lane & 15;

    const size_t base = (size_t)b * PERB + (size_t)h * 32768;
    const ushort_t* Qg = Q + base;
    const ushort_t* Kg = K + base;
    const ushort_t* Vg = V + base;
    const float* rbh = relb + h * 3969;

    // ---- stage Q [32s x 128m] into Pb (granule layout), then read frags ----
    {
        const int mm = tid & 127;
        const int sg = tid >> 7;
        union { bf16x8 v; uint16_t u[8]; } g0, g1;
#pragma unroll
        for (int j = 0; j < 8; ++j)
            g0.u[j] = Qg[(size_t)(sg * 16 + j) * 1024 + m0 + mm];
#pragma unroll
        for (int j = 0; j < 8; ++j)
            g1.u[j] = Qg[(size_t)(sg * 16 + 8 + j) * 1024 + m0 + mm];
        *(bf16x8*)(Pb + (sg * 2 + 0) * 2048 + mm * 16) = g0.v;
        *(bf16x8*)(Pb + (sg * 2 + 1) * 2048 + mm * 16) = g1.v;
    }
    __syncthreads();
    bf16x8 qfrag[8];
#pragma unroll
    for (int msub = 0; msub < 8; ++msub)
        qfrag[msub] = *(const bf16x8*)(Pb + quad * 2048 + (msub * 16 + c) * 16);

    // per-msub bias m-offset: idx = noff(n) + moff(m)
    int moff[8];
#pragma unroll
    for (int msub = 0; msub < 8; ++msub) {
        const int m = m0 + msub * 16 + c;
        moff[msub] = 1984 - (m >> 5) * 63 - (m & 31);
    }

    // accumulators
    f32x4 oacc[2][2], dacc[2];
#pragma unroll
    for (int i = 0; i < 2; ++i) {
        dacc[i] = (f32x4){0.f, 0.f, 0.f, 0.f};
#pragma unroll
        for (int j = 0; j < 2; ++j) oacc[i][j] = (f32x4){0.f, 0.f, 0.f, 0.f};
    }
    bf16x8 onesf;
#pragma unroll
    for (int j = 0; j < 8; ++j) onesf[j] = (short)0x3F80;

    // staging thread coords + hoisted LDS addresses
    const int knn = tid & 63, ksg = tid >> 6;   // K: 8 s-values for column knn
    const int vs  = tid >> 3, vng = tid & 7;    // V: unit16 vng of row vs
    const int kWr = ksg * 1024 + knn * 16;
    const int vWr = vs * 128 + ((vng ^ (vs & 7)) << 4);
    const int kRd = quad * 1024 + (w * 16 + c) * 16;
    const int pWr = c * 128 + (((2 * w + (quad >> 1)) ^ (c & 7)) << 4) + ((quad & 1) << 3);
    const int c7  = c & 7;

    // prologue: prefetch chunk 0
    uint32_t kpre[8]; bf16x8 vpre;
#pragma unroll
    for (int j = 0; j < 8; ++j) kpre[j] = Kg[(size_t)(ksg * 8 + j) * 1024 + knn];
    vpre = *(const bf16x8*)&Vg[(size_t)vs * 1024 + vng * 8];

    for (int ch = 0; ch < 16; ++ch) {
        const int n0c = ch << 6;
        const int cb  = ch & 1;

        // ---- write prefetched K/V to LDS ----
        {
            uint4 kp;
            kp.x = kpre[0] | (kpre[1] << 16);
            kp.y = kpre[2] | (kpre[3] << 16);
            kp.z = kpre[4] | (kpre[5] << 16);
            kp.w = kpre[6] | (kpre[7] << 16);
            *(uint4*)(Kl + kWr) = kp;
            *(bf16x8*)(Vl + cb * 4096 + vWr) = vpre;
        }
        __syncthreads();   // staging visible; prev PV done for all waves

        // ---- prefetch next chunk into regs (overlaps S phase) ----
        {
            const int n0n = ((ch + 1) & 15) << 6;
#pragma unroll
            for (int j = 0; j < 8; ++j)
                kpre[j] = Kg[(size_t)(ksg * 8 + j) * 1024 + n0n + knn];
            vpre = *(const bf16x8*)&Vg[(size_t)vs * 1024 + n0n + vng * 8];
        }

        // ---- S phase ----
        const bf16x8 kf = *(const bf16x8*)(Kl + kRd);
        f32x4 sacc[8];
#pragma unroll
        for (int msub = 0; msub < 8; ++msub) {
            const f32x4 z = {0.f, 0.f, 0.f, 0.f};
            sacc[msub] = __builtin_amdgcn_mfma_f32_16x16x32_bf16(kf, qfrag[msub], z, 0, 0, 0);
        }

        // ---- bias (global, L1/L2-hit) + exp2 + trunc-pack + P write ----
        const int nbase = n0c + w * 16 + quad * 4;
        const int nidx0 = (nbase >> 5) * 63 + (nbase & 31);  // 4 consecutive ints follow
#pragma unroll
        for (int msub = 0; msub < 8; ++msub) {
            const float* bp = rbh + nidx0 + moff[msub];
            float p[4];
#pragma unroll
            for (int r = 0; r < 4; ++r)
                p[r] = __builtin_amdgcn_exp2f(fmaf(bp[r], LOG2EF, sacc[msub][r] * C1F));
            uint2 pk;
            pk.x = __builtin_amdgcn_perm(__float_as_uint(p[1]), __float_as_uint(p[0]), 0x07060302u);
            pk.y = __builtin_amdgcn_perm(__float_as_uint(p[3]), __float_as_uint(p[2]), 0x07060302u);
            *(uint2*)(Pb + msub * 2048 + pWr) = pk;
        }
        __syncthreads();   // P (and V) ready for PV

        // ---- PV phase: wave w owns msub {2w, 2w+1} ----
#pragma unroll
        for (int kstep = 0; kstep < 2; ++kstep) {
            const int u = ((kstep * 4 + quad) ^ c7) << 4;
            const bf16x8 vf0 = *(const bf16x8*)(Vl + cb * 4096 + c * 128 + u);
            const bf16x8 vf1 = *(const bf16x8*)(Vl + cb * 4096 + (16 + c) * 128 + u);
#pragma unroll
            for (int mi = 0; mi < 2; ++mi) {
                const bf16x8 pf = *(const bf16x8*)(Pb + ((w * 2 + mi) * 16 + c) * 128 + u);
                oacc[0][mi] = __builtin_amdgcn_mfma_f32_16x16x32_bf16(vf0, pf, oacc[0][mi], 0, 0, 0);
                oacc[1][mi] = __builtin_amdgcn_mfma_f32_16x16x32_bf16(vf1, pf, oacc[1][mi], 0, 0, 0);
                dacc[mi]    = __builtin_amdgcn_mfma_f32_16x16x32_bf16(onesf, pf, dacc[mi], 0, 0, 0);
            }
        }
    }

    // ---- epilogue: scale by 1/denominator, write O ----
    ushort_t* Ob = O + base;
#pragma unroll
    for (int mi = 0; mi < 2; ++mi) {
        const float inv = 1.0f / dacc[mi][0];
        const int m = m0 + (w * 2 + mi) * 16 + c;
#pragma unroll
        for (int ssub = 0; ssub < 2; ++ssub)
#pragma unroll
            for (int r = 0; r < 4; ++r)
                Ob[(size_t)(ssub * 16 + quad * 4 + r) * 1024 + m] = f2bf(oacc[ssub][mi][r] * inv);
    }
}

// ---------------------------------------------------------------------------
// Kernel 4: MFMA output projection + bias + residual. Unchanged.
// ---------------------------------------------------------------------------
__global__ __launch_bounds__(256, 4) void oproj_kernel(
    const ushort_t* __restrict__ A, const ushort_t* __restrict__ wo,
    const float* __restrict__ bo, const float* __restrict__ x,
    float* __restrict__ out)
{
    __shared__ __align__(16) ushort_t Al[512 * 8];
    __shared__ __align__(16) ushort_t Wl[512 * 8];

    const int blk = blockIdx.x;
    const int m0  = (blk >> 2) << 6;
    const int n0  = (blk & 3) << 6;
    const int tid = threadIdx.x;
    const int w    = tid >> 6;
    const int lane = tid & 63;
    const int quad = lane >> 4;
    const int c    = lane & 15;

    f32x4 acc[4];
#pragma unroll
    for (int i = 0; i < 4; ++i) acc[i] = (f32x4){0.f, 0.f, 0.f, 0.f};

    for (int kc = 0; kc < 4; ++kc) {
        const int k0 = kc << 6;
        __syncthreads();
#pragma unroll
        for (int i = 0; i < 2; ++i) {
            const int id = tid + i * 256;
            const int kq = id >> 6, mn = id & 63;
            *(bf16x8*)&Al[id * 8] = *(const bf16x8*)&A [(size_t)(m0 + mn) * 256 + k0 + kq * 8];
            *(bf16x8*)&Wl[id * 8] = *(const bf16x8*)&wo[(size_t)(n0 + mn) * 256 + k0 + kq * 8];
        }
        __syncthreads();
#pragma unroll
        for (int ks = 0; ks < 2; ++ks) {
            const int kq = ks * 4 + quad;
            const bf16x8 bw = *(const bf16x8*)&Wl[(kq * 64 + w * 16 + c) * 8];
#pragma unroll
            for (int msub = 0; msub < 4; ++msub) {
                const bf16x8 af = *(const bf16x8*)&Al[(kq * 64 + msub * 16 + c) * 8];
                acc[msub] = __builtin_amdgcn_mfma_f32_16x16x32_bf16(bw, af, acc[msub], 0, 0, 0);
            }
        }
    }

    const int n = n0 + w * 16 + quad * 4;
    const float4 bo4 = *(const float4*)&bo[n];
#pragma unroll
    for (int msub = 0; msub < 4; ++msub) {
        const size_t g = (size_t)(m0 + msub * 16 + c) * 256 + n;
        const float4 r = *(const float4*)&x[g];
        float4 t;
        t.x = acc[msub][0] + bo4.x + r.x;
        t.y = acc[msub][1] + bo4.y + r.y;
        t.z = acc[msub][2] + bo4.z + r.z;
        t.w = acc[msub][3] + bo4.w + r.w;
        *(float4*)&out[g] = t;
    }
}

// ---------------------------------------------------------------------------
extern "C" void kernel_launch(void* const* d_in, const int* in_sizes, int n_in,
                              void* d_out, int out_size, void* d_ws, size_t ws_size,
                              hipStream_t stream)
{
    (void)in_sizes; (void)n_in; (void)out_size; (void)ws_size;
    const float* x   = (const float*)d_in[0];
    const float* lng = (const float*)d_in[1];
    const float* lnb = (const float*)d_in[2];
    const float* wq  = (const float*)d_in[3];
    const float* bq  = (const float*)d_in[4];
    const float* wk  = (const float*)d_in[5];
    const float* bk  = (const float*)d_in[6];
    const float* wv  = (const float*)d_in[7];
    const float* bv  = (const float*)d_in[8];
    const float* wo  = (const float*)d_in[9];
    const float* bo  = (const float*)d_in[10];
    const float* rb  = (const float*)d_in[11];
    // d_in[12] (rel_idx) unused: index recomputed analytically in-kernel.

    ushort_t* ws = (ushort_t*)d_ws;
    ushort_t* Xbf = ws;                       // 4194304 elems each
    ushort_t* Qbf = ws + 1 * 4194304;
    ushort_t* Kbf = ws + 2 * 4194304;
    ushort_t* Vbf = ws + 3 * 4194304;
    ushort_t* Obf = ws + 4 * 4194304;
    ushort_t* Wqb = ws + 5 * 4194304;
    ushort_t* Wkb = Wqb + 65536;
    ushort_t* Wvb = Wkb + 65536;
    ushort_t* Wob = Wvb + 65536;
    float* out = (float*)d_out;

    hipLaunchKernelGGL(wcvt_kernel,  dim3(256),  dim3(256), 0, stream,
                       wq, wk, wv, wo, Wqb, Wkb, Wvb, Wob);
    hipLaunchKernelGGL(ln_kernel,    dim3(256),  dim3(256), 0, stream, x, lng, lnb, Xbf);
    hipLaunchKernelGGL(qkv_kernel,   dim3(1024), dim3(256), 0, stream,
                       Xbf, Wqb, bq, Wkb, bk, Wvb, bv, Qbf, Kbf, Vbf);
    hipLaunchKernelGGL(attn_kernel,  dim3(1024), dim3(256), 0, stream, Qbf, Kbf, Vbf, rb, Obf);
    hipLaunchKernelGGL(oproj_kernel, dim3(1024), dim3(256), 0, stream, Obf, Wob, bo, x, out);
}